// Round 1
// baseline (61.446 us; speedup 1.0000x reference)
//
#include <hip/hip_runtime.h>
#include <math.h>

#define B_ 32
#define C_ 128
#define L_ 4096
#define G_ 8

// ---------------- Kernel 1: per-(b,c) min/max partials ----------------
// grid = B_*C_ blocks of 256 threads; block p handles x[p*4096 .. p*4096+4095]
__global__ __launch_bounds__(256) void k_minmax(const float* __restrict__ x,
                                                float* __restrict__ pmin,
                                                float* __restrict__ pmax) {
    const int p = blockIdx.x;            // p = b*C_ + c
    const int tid = threadIdx.x;
    const float4* xv = (const float4*)(x + (size_t)p * L_);
    float vmin = INFINITY, vmax = -INFINITY;
#pragma unroll
    for (int i = 0; i < 4; ++i) {
        float4 v = xv[i * 256 + tid];
        vmin = fminf(vmin, fminf(fminf(v.x, v.y), fminf(v.z, v.w)));
        vmax = fmaxf(vmax, fmaxf(fmaxf(v.x, v.y), fmaxf(v.z, v.w)));
    }
#pragma unroll
    for (int off = 32; off > 0; off >>= 1) {
        vmin = fminf(vmin, __shfl_down(vmin, off, 64));
        vmax = fmaxf(vmax, __shfl_down(vmax, off, 64));
    }
    __shared__ float smin[4], smax[4];
    const int wave = tid >> 6, lane = tid & 63;
    if (lane == 0) { smin[wave] = vmin; smax[wave] = vmax; }
    __syncthreads();
    if (tid == 0) {
        float m0 = fminf(fminf(smin[0], smin[1]), fminf(smin[2], smin[3]));
        float m1 = fmaxf(fmaxf(smax[0], smax[1]), fmaxf(smax[2], smax[3]));
        int b = p >> 7, c = p & (C_ - 1);
        pmin[c * B_ + b] = m0;
        pmax[c * B_ + b] = m1;
    }
}

// ---------------- Kernel 2: group quantization + softmax + coeffs ----------------
// 1 block of 128 threads (thread = channel).
__global__ __launch_bounds__(128) void k_prep(const float* __restrict__ pmin,
                                              const float* __restrict__ pmax,
                                              const float* __restrict__ alpha,
                                              float* __restrict__ wq,    // [G_][C_]
                                              float* __restrict__ offv,  // [C_]
                                              float* __restrict__ scv,   // [G_]
                                              float* __restrict__ zpv) { // [G_]
    const int c = threadIdx.x; // 0..127
    __shared__ float smin[C_], smax[C_];
    __shared__ int markN[C_], markX[C_];
    __shared__ float gmin[G_], gmax[G_];
    __shared__ float ssc[G_], szp[G_];

    // reduce partials + INIT clamps (ch_min = min(.., -4), ch_max = max(.., 6))
    float a = INFINITY, b = -INFINITY;
    for (int j = 0; j < B_; ++j) {
        a = fminf(a, pmin[c * B_ + j]);
        b = fmaxf(b, pmax[c * B_ + j]);
    }
    a = fminf(a, -4.0f);
    b = fmaxf(b, 6.0f);
    smin[c] = a; smax[c] = b;
    __syncthreads();

    // global range of each 128-vector (redundant per-thread scan; broadcasts)
    float rminN = INFINITY, rmaxN = -INFINITY, rminX = INFINITY, rmaxX = -INFINITY;
    for (int j = 0; j < C_; ++j) {
        float u = smin[j], v = smax[j];
        rminN = fminf(rminN, u); rmaxN = fmaxf(rmaxN, u);
        rminX = fminf(rminX, v); rmaxX = fmaxf(rmaxX, v);
    }
    const float divN = rmaxN - rminN, divX = rmaxX - rminX;
    float bN[G_ + 1], bX[G_ + 1];
#pragma unroll
    for (int m = 0; m <= G_; ++m) {
        // replicate: rmin + div * (m/8) in f32, exact order
        bN[m] = rminN + __fmul_rn(divN, (float)m * 0.125f);
        bX[m] = rminX + __fmul_rn(divX, (float)m * 0.125f);
    }
    // mark: ascending m, later bins overwrite at shared edges
    int mN = 0, mX = 0;
    const float vN = smin[c], vX = smax[c];
#pragma unroll
    for (int m = 0; m < G_; ++m) {
        if (vN >= bN[m] && vN <= bN[m + 1]) mN = m + 1;
        if (vX >= bX[m] && vX <= bX[m + 1]) mX = m + 1;
    }
    markN[c] = mN; markX[c] = mX;
    __syncthreads();

    if (c < G_) {               // bin stats for ch_min ('min')
        float s = INFINITY; bool found = false;
        for (int j = 0; j < C_; ++j)
            if (markN[j] == c + 1) { s = fminf(s, smin[j]); found = true; }
        gmin[c] = found ? s : bN[c + 1];
    } else if (c < 2 * G_) {    // bin stats for ch_max ('max')
        const int g = c - G_;
        float s = -INFINITY; bool found = false;
        for (int j = 0; j < C_; ++j)
            if (markX[j] == g + 1) { s = fmaxf(s, smax[j]); found = true; }
        gmax[g] = found ? s : bX[g + 1];
    }
    __syncthreads();

    if (c < G_) {
        const float left = gmin[c], right = gmax[c];
        const float sc = 255.0f / fmaxf(right - left, 1e-8f);
        const float zp = rintf(__fmul_rn(sc, left)) + 128.0f;
        ssc[c] = sc; szp[c] = zp;
        scv[c] = sc; zpv[c] = zp;
    }
    __syncthreads();

    // softmax over G for channel c; fold: w = sw/scale, off = sum w*zp
    float av[G_];
    float amax = -INFINITY;
#pragma unroll
    for (int g = 0; g < G_; ++g) { av[g] = alpha[g * C_ + c]; amax = fmaxf(amax, av[g]); }
    float sum = 0.0f;
#pragma unroll
    for (int g = 0; g < G_; ++g) { av[g] = expf(av[g] - amax); sum += av[g]; }
    float offc = 0.0f;
#pragma unroll
    for (int g = 0; g < G_; ++g) {
        float w = (av[g] / sum) / ssc[g];
        wq[g * C_ + c] = w;
        offc += w * szp[g];
    }
    offv[c] = offc;
}

// ---------------- Kernel 3: elementwise apply ----------------
// out[idx] = off[c] + sum_g w[g,c] * clamp(rint(s_g*x - zp_g), -128, 127)
// block of 256 threads covers 1024 consecutive elements -> single channel/block.
__global__ __launch_bounds__(256) void k_apply(const float* __restrict__ x,
                                               const float* __restrict__ wq,
                                               const float* __restrict__ offv,
                                               const float* __restrict__ scv,
                                               const float* __restrict__ zpv,
                                               float* __restrict__ out) {
    const int c = (blockIdx.x >> 2) & (C_ - 1);   // 4 blocks per (b,c) row
    float s[G_], z[G_], w[G_];
#pragma unroll
    for (int g = 0; g < G_; ++g) {
        s[g] = scv[g];
        z[g] = zpv[g];
        w[g] = wq[g * C_ + c];
    }
    const float offc = offv[c];
    const size_t idx = (size_t)blockIdx.x * 256 + threadIdx.x;
    float4 xv = ((const float4*)x)[idx];
    float in[4] = {xv.x, xv.y, xv.z, xv.w};
    float r[4];
#pragma unroll
    for (int i = 0; i < 4; ++i) {
        float acc = offc;
#pragma unroll
        for (int g = 0; g < G_; ++g) {
            float t = __fmul_rn(s[g], in[i]) - z[g];   // no fma contraction
            float q = rintf(t);                        // round half-to-even
            q = fminf(fmaxf(q, -128.0f), 127.0f);
            acc = fmaf(w[g], q, acc);
        }
        r[i] = acc;
    }
    ((float4*)out)[idx] = make_float4(r[0], r[1], r[2], r[3]);
}

extern "C" void kernel_launch(void* const* d_in, const int* in_sizes, int n_in,
                              void* d_out, int out_size, void* d_ws, size_t ws_size,
                              hipStream_t stream) {
    const float* x = (const float*)d_in[0];       // [32,128,4096]
    const float* alpha = (const float*)d_in[1];   // [8,128]
    float* out = (float*)d_out;
    float* ws = (float*)d_ws;

    float* pmin = ws;              // [C_*B_] = 4096
    float* pmax = ws + 4096;       // 4096
    float* wq   = ws + 8192;       // [G_*C_] = 1024
    float* offv = ws + 9216;       // 128
    float* scv  = ws + 9344;       // 8
    float* zpv  = ws + 9352;       // 8

    k_minmax<<<B_ * C_, 256, 0, stream>>>(x, pmin, pmax);
    k_prep<<<1, 128, 0, stream>>>(pmin, pmax, alpha, wq, offv, scv, zpv);
    k_apply<<<(B_ * C_ * L_) / 1024, 256, 0, stream>>>(x, wq, offv, scv, zpv, out);
}